// Round 3
// baseline (31943.756 us; speedup 1.0000x reference)
//
#include <hip/hip_runtime.h>
#include <math.h>

#define T_STEPS 2048
#define B_SZ 32
#define F_SZ 512
#define H_SZ 512
#define H4_SZ 2048
#define NC_SZ 64
#define NBLK 64
#define RING (B_SZ * H_SZ)   // 16384 fp16 elements per ring slot
#define FLAG_STRIDE 32       // u32s -> 128 B: one LLC line per block's flag

typedef _Float16 f16x8 __attribute__((ext_vector_type(8)));
typedef float f32x4 __attribute__((ext_vector_type(4)));

#define TIDX(l, w, rt, ct) (((((l)*4 + (w))*2 + (rt))*2 + (ct)))

// Coherence-point (LLC) 16B load as two 8B relaxed agent atomics: emits
// global_load_dwordx2 sc0 sc1 -> bypasses (possibly stale) per-XCD L2.
__device__ __forceinline__ f16x8 load_h8_cp(const _Float16* p) {
    union { f16x8 v; unsigned long long q[2]; } u;
    u.q[0] = __hip_atomic_load((const unsigned long long*)p,
                               __ATOMIC_RELAXED, __HIP_MEMORY_SCOPE_AGENT);
    u.q[1] = __hip_atomic_load((const unsigned long long*)(p + 4),
                               __ATOMIC_RELAXED, __HIP_MEMORY_SCOPE_AGENT);
    return u.v;
}

// Single-cluster persistent 2-layer LSTM.
// 64 blocks x 256 thr. Block j owns hidden units [8j,8j+8) of BOTH layers
// (c-state in regs). Full batch B=32 per block via 2 MFMA row-tiles.
// Iter it: layer0 t=it, layer1 t=it-1 -> one distributed flag-barrier/iter.
// Flags are padded one-per-LLC-line; each poll lane spins on its own line
// (round-2 lesson: packed flags + 4096 spinners serialized the LLC).
__global__ __launch_bounds__(256, 1) void lstm_persistent(
    const float* __restrict__ feats,
    const float* __restrict__ Wi0, const float* __restrict__ Wh0,
    const float* __restrict__ bh0,
    const float* __restrict__ Wi1, const float* __restrict__ Wh1,
    const float* __restrict__ bh1,
    const float* __restrict__ Wout, const float* __restrict__ bout,
    float* __restrict__ out,
    _Float16* __restrict__ h0buf,   // [2][32][512] fp16 ring
    _Float16* __restrict__ h1buf,   // [2][32][512] fp16 ring
    float* __restrict__ h1fin,      // [32][512] f32 final h1
    unsigned* __restrict__ flags)   // [64 * FLAG_STRIDE] per-block flags, padded
{
    const int tid   = threadIdx.x;
    const int lane  = tid & 63;
    const int wv    = tid >> 6;          // wave 0..3 = K-quarter of stacked K=1024
    const int jb    = blockIdx.x;        // 0..63
    const int hbase = jb * 8;
    const int rlane = lane & 15;
    const int klo   = (lane >> 4) * 8;

    __shared__ float zs[32 * 272];       // 32 tiles of 16x17 f32 partials
    __shared__ float ps[256];

    // ---- one-time: weight fragments (fp16) ----
    // layer0 stacked K: [Wi0(512); Wh0(512)], A0 = [x | h0]
    // layer1 stacked K: [Wh1(512); Wi1(512)], A1 = [h1 | h0]
    // B frag 16x16x32: lane holds col=lane&15, k=(lane>>4)*8+i  (verified r1)
    f16x8 wf0[2][8], wf1[2][8];
    #pragma unroll
    for (int ct = 0; ct < 2; ++ct) {
        const int cc   = ct * 16 + rlane;
        const int jcol = (cc >> 3) * H_SZ + hbase + (cc & 7);
        #pragma unroll
        for (int ks = 0; ks < 8; ++ks) {
            const int k0 = 256 * wv + 32 * ks + klo;
            f16x8 f0, f1;
            #pragma unroll
            for (int i = 0; i < 8; ++i) {
                const int k = k0 + i;
                const float v0 = (k < H_SZ) ? Wi0[(size_t)k * H4_SZ + jcol]
                                            : Wh0[(size_t)(k - H_SZ) * H4_SZ + jcol];
                const float v1 = (k < H_SZ) ? Wh1[(size_t)k * H4_SZ + jcol]
                                            : Wi1[(size_t)(k - H_SZ) * H4_SZ + jcol];
                f0[i] = (_Float16)v0;
                f1[i] = (_Float16)v1;
            }
            wf0[ct][ks] = f0;
            wf1[ct][ks] = f1;
        }
    }

    // gate-thread mapping: all 256 threads, one (batch,unit) each
    const int gb = tid >> 3, gu = tid & 7;
    const int grow = gb & 15, grt = gb >> 4;
    float c0 = 0.f, c1 = 0.f;
    float bias0[4], bias1[4];
    #pragma unroll
    for (int g = 0; g < 4; ++g) {
        bias0[g] = bh0[g * H_SZ + hbase + gu];
        bias1[g] = bh1[g * H_SZ + hbase + gu];
    }

    f16x8 xf[2][8];   // prefetched+converted x fragments (waves 0,1)

#define PREFETCH_X(tt_) do {                                                         \
    if (wv < 2 && (tt_) < T_STEPS) {                                                 \
        _Pragma("unroll")                                                            \
        for (int rt = 0; rt < 2; ++rt) {                                             \
            const float* xr = feats                                                  \
                + ((size_t)(rt * 16 + rlane) * T_STEPS + (size_t)(tt_)) * F_SZ       \
                + 256 * wv + klo;                                                    \
            _Pragma("unroll")                                                        \
            for (int ks = 0; ks < 8; ++ks) {                                         \
                const float4 p0 = *(const float4*)(xr + 32 * ks);                    \
                const float4 p1 = *(const float4*)(xr + 32 * ks + 4);                \
                f16x8 t;                                                             \
                t[0] = (_Float16)p0.x; t[1] = (_Float16)p0.y;                        \
                t[2] = (_Float16)p0.z; t[3] = (_Float16)p0.w;                        \
                t[4] = (_Float16)p1.x; t[5] = (_Float16)p1.y;                        \
                t[6] = (_Float16)p1.z; t[7] = (_Float16)p1.w;                        \
                xf[rt][ks] = t;                                                      \
            }                                                                        \
        }                                                                            \
    }                                                                                \
} while (0)

    PREFETCH_X(0);

    for (int it = 0; it <= T_STEPS; ++it) {
        // ---- distributed barrier: each poll lane owns one padded flag line ----
        if (tid < 64) {
            while (__hip_atomic_load(&flags[(size_t)lane * FLAG_STRIDE],
                                     __ATOMIC_RELAXED, __HIP_MEMORY_SCOPE_AGENT)
                   < (unsigned)it) { }
        }
        __syncthreads();

        // ---- h fragments from LLC ----
        // wv>=2: h0[it-1] (slot (it+1)&1), shared by layer0 & layer1
        // wv<2 : h1[it-2] (slot it&1) for layer1
        f16x8 hA[2][8];
        if (wv >= 2) {
            const _Float16* hp = h0buf + (size_t)((it + 1) & 1) * RING;
            #pragma unroll
            for (int rt = 0; rt < 2; ++rt)
                #pragma unroll
                for (int ks = 0; ks < 8; ++ks)
                    hA[rt][ks] = load_h8_cp(hp + (rt * 16 + rlane) * H_SZ
                                            + 256 * (wv - 2) + 32 * ks + klo);
        } else if (it > 0) {
            const _Float16* hp = h1buf + (size_t)(it & 1) * RING;
            #pragma unroll
            for (int rt = 0; rt < 2; ++rt)
                #pragma unroll
                for (int ks = 0; ks < 8; ++ks)
                    hA[rt][ks] = load_h8_cp(hp + (rt * 16 + rlane) * H_SZ
                                            + 256 * wv + 32 * ks + klo);
        }

        const int r0 = (lane >> 4) * 4, ccl = lane & 15;

        // ---- layer0 MFMA (t=it): A = x (wv<2, ready in regs) or h0 (wv>=2) ----
        if (it < T_STEPS) {
            f32x4 a00 = {0,0,0,0}, a01 = {0,0,0,0}, a10 = {0,0,0,0}, a11 = {0,0,0,0};
            #pragma unroll
            for (int ks = 0; ks < 8; ++ks) {
                const f16x8 ar0 = (wv < 2) ? xf[0][ks] : hA[0][ks];
                const f16x8 ar1 = (wv < 2) ? xf[1][ks] : hA[1][ks];
                a00 = __builtin_amdgcn_mfma_f32_16x16x32_f16(ar0, wf0[0][ks], a00, 0, 0, 0);
                a01 = __builtin_amdgcn_mfma_f32_16x16x32_f16(ar0, wf0[1][ks], a01, 0, 0, 0);
                a10 = __builtin_amdgcn_mfma_f32_16x16x32_f16(ar1, wf0[0][ks], a10, 0, 0, 0);
                a11 = __builtin_amdgcn_mfma_f32_16x16x32_f16(ar1, wf0[1][ks], a11, 0, 0, 0);
            }
            #pragma unroll
            for (int q = 0; q < 4; ++q) {
                zs[TIDX(0, wv, 0, 0) * 272 + (r0 + q) * 17 + ccl] = a00[q];
                zs[TIDX(0, wv, 0, 1) * 272 + (r0 + q) * 17 + ccl] = a01[q];
                zs[TIDX(0, wv, 1, 0) * 272 + (r0 + q) * 17 + ccl] = a10[q];
                zs[TIDX(0, wv, 1, 1) * 272 + (r0 + q) * 17 + ccl] = a11[q];
            }
        }
        // ---- layer1 MFMA (t=it-1): A = h1 (wv<2) or h0 (wv>=2) = hA ----
        if (it > 0) {
            f32x4 a00 = {0,0,0,0}, a01 = {0,0,0,0}, a10 = {0,0,0,0}, a11 = {0,0,0,0};
            #pragma unroll
            for (int ks = 0; ks < 8; ++ks) {
                a00 = __builtin_amdgcn_mfma_f32_16x16x32_f16(hA[0][ks], wf1[0][ks], a00, 0, 0, 0);
                a01 = __builtin_amdgcn_mfma_f32_16x16x32_f16(hA[0][ks], wf1[1][ks], a01, 0, 0, 0);
                a10 = __builtin_amdgcn_mfma_f32_16x16x32_f16(hA[1][ks], wf1[0][ks], a10, 0, 0, 0);
                a11 = __builtin_amdgcn_mfma_f32_16x16x32_f16(hA[1][ks], wf1[1][ks], a11, 0, 0, 0);
            }
            #pragma unroll
            for (int q = 0; q < 4; ++q) {
                zs[TIDX(1, wv, 0, 0) * 272 + (r0 + q) * 17 + ccl] = a00[q];
                zs[TIDX(1, wv, 0, 1) * 272 + (r0 + q) * 17 + ccl] = a01[q];
                zs[TIDX(1, wv, 1, 0) * 272 + (r0 + q) * 17 + ccl] = a10[q];
                zs[TIDX(1, wv, 1, 1) * 272 + (r0 + q) * 17 + ccl] = a11[q];
            }
        }
        __syncthreads();

        // ---- gates: reduce 4 K-partials, update c, emit h (relaxed agent stores) ----
        if (it < T_STEPS) {
            float z[4];
            #pragma unroll
            for (int g = 0; g < 4; ++g) {
                const int cc = g * 8 + gu, ct = cc >> 4, col = cc & 15;
                float v = bias0[g];
                #pragma unroll
                for (int w = 0; w < 4; ++w)
                    v += zs[TIDX(0, w, grt, ct) * 272 + grow * 17 + col];
                z[g] = v;
            }
            const float ig = 1.f / (1.f + expf(-z[0]));
            const float fg = 1.f / (1.f + expf(-z[1]));
            const float gg = tanhf(z[2]);
            const float og = 1.f / (1.f + expf(-z[3]));
            c0 = fg * c0 + ig * gg;
            const float hv = og * tanhf(c0);
            const float hpart = __shfl_xor(hv, 1);
            if ((gu & 1) == 0) {   // pack 2 fp16 -> one u32 atomic store
                union { _Float16 h; unsigned short s; } lo, hi;
                lo.h = (_Float16)hv; hi.h = (_Float16)hpart;
                const unsigned pk = (unsigned)lo.s | ((unsigned)hi.s << 16);
                __hip_atomic_store(
                    (unsigned*)(h0buf + (size_t)(it & 1) * RING + gb * H_SZ + hbase + gu),
                    pk, __ATOMIC_RELAXED, __HIP_MEMORY_SCOPE_AGENT);
            }
        }
        if (it > 0) {
            float z[4];
            #pragma unroll
            for (int g = 0; g < 4; ++g) {
                const int cc = g * 8 + gu, ct = cc >> 4, col = cc & 15;
                float v = bias1[g];
                #pragma unroll
                for (int w = 0; w < 4; ++w)
                    v += zs[TIDX(1, w, grt, ct) * 272 + grow * 17 + col];
                z[g] = v;
            }
            const float ig = 1.f / (1.f + expf(-z[0]));
            const float fg = 1.f / (1.f + expf(-z[1]));
            const float gg = tanhf(z[2]);
            const float og = 1.f / (1.f + expf(-z[3]));
            c1 = fg * c1 + ig * gg;
            const float hv = og * tanhf(c1);
            const float hpart = __shfl_xor(hv, 1);
            if ((gu & 1) == 0) {
                union { _Float16 h; unsigned short s; } lo, hi;
                lo.h = (_Float16)hv; hi.h = (_Float16)hpart;
                const unsigned pk = (unsigned)lo.s | ((unsigned)hi.s << 16);
                __hip_atomic_store(
                    (unsigned*)(h1buf + (size_t)((it + 1) & 1) * RING + gb * H_SZ + hbase + gu),
                    pk, __ATOMIC_RELAXED, __HIP_MEMORY_SCOPE_AGENT);
            }
            if (it == T_STEPS) {
                union { float f; unsigned u; } cv; cv.f = hv;
                __hip_atomic_store((unsigned*)(h1fin + gb * H_SZ + hbase + gu),
                                   cv.u, __ATOMIC_RELAXED, __HIP_MEMORY_SCOPE_AGENT);
            }
        }
        // drain all stores to the coherence point, then arrive on own line
        asm volatile("s_waitcnt vmcnt(0)" ::: "memory");
        __syncthreads();
        if (tid == 0)
            __hip_atomic_store(&flags[(size_t)jb * FLAG_STRIDE], (unsigned)(it + 1),
                               __ATOMIC_RELAXED, __HIP_MEMORY_SCOPE_AGENT);

        // tail: prefetch + convert x[it+1] during barrier slack
        PREFETCH_X(it + 1);
    }

    // final barrier: all h1fin stores visible
    if (tid < 64) {
        while (__hip_atomic_load(&flags[(size_t)lane * FLAG_STRIDE],
                                 __ATOMIC_RELAXED, __HIP_MEMORY_SCOPE_AGENT)
               < (unsigned)(T_STEPS + 1)) { }
    }
    __syncthreads();

    // ---- output head: block jb -> out[:, jb] ----
    {
        const int b = tid & 31, kc = tid >> 5;
        float part = 0.f;
        for (int k = kc * 64; k < kc * 64 + 64; ++k) {
            union { unsigned u; float f; } cv;
            cv.u = __hip_atomic_load((const unsigned*)(h1fin + b * H_SZ + k),
                                     __ATOMIC_RELAXED, __HIP_MEMORY_SCOPE_AGENT);
            part += cv.f * Wout[(size_t)k * NC_SZ + jb];
        }
        ps[kc * 32 + b] = part;
        __syncthreads();
        if (tid < 32) {
            float acc = bout[jb];
            #pragma unroll
            for (int c = 0; c < 8; ++c) acc += ps[c * 32 + tid];
            out[tid * NC_SZ + jb] = acc;
        }
    }
#undef PREFETCH_X
}

extern "C" void kernel_launch(void* const* d_in, const int* in_sizes, int n_in,
                              void* d_out, int out_size, void* d_ws, size_t ws_size,
                              hipStream_t stream) {
    const float* feats = (const float*)d_in[0];
    const float* Wi0   = (const float*)d_in[1];
    const float* Wh0   = (const float*)d_in[2];
    const float* bh0   = (const float*)d_in[3];
    const float* Wi1   = (const float*)d_in[4];
    const float* Wh1   = (const float*)d_in[5];
    const float* bh1   = (const float*)d_in[6];
    const float* Wout  = (const float*)d_in[7];
    const float* bout  = (const float*)d_in[8];

    char* ws = (char*)d_ws;
    _Float16* h0buf = (_Float16*)(ws);            // 64 KB
    _Float16* h1buf = (_Float16*)(ws + 65536);    // 64 KB
    float*    h1fin = (float*)(ws + 131072);      // 64 KB
    unsigned* flags = (unsigned*)(ws + 196608);   // 64 * 128 B = 8 KB

    // zero rings (h[-1]=h[-2]=0), final buf, flags — every call (determinism;
    // graph replays reuse ws, so stale flags MUST be cleared each call)
    hipMemsetAsync(d_ws, 0, 204800, stream);

    lstm_persistent<<<dim3(NBLK), dim3(256), 0, stream>>>(
        feats, Wi0, Wh0, bh0, Wi1, Wh1, bh1, Wout, bout,
        (float*)d_out, h0buf, h1buf, h1fin, flags);
}